// Round 3
// baseline (965.162 us; speedup 1.0000x reference)
//
#include <hip/hip_runtime.h>

#define DIM 4096
#define MROWS 16384
#define EPSV 1e-5f
#define NKT (DIM / 64)  // 64 K-tiles of BK=64

typedef __attribute__((ext_vector_type(8))) short short8;
typedef __attribute__((ext_vector_type(4))) float floatx4;

__device__ __forceinline__ unsigned short f2bf(float f) {
  union { float f; unsigned u; } c; c.f = f;
  unsigned r = c.u + 0x7fffu + ((c.u >> 16) & 1u);   // round-to-nearest-even
  return (unsigned short)(r >> 16);
}

struct alignas(16) US8 { unsigned short u[8]; };

// ---------------- LayerNorm: one wave per row, no barriers, 16B stores ----------------
__global__ __launch_bounds__(256) void ln_kernel(const float* __restrict__ x,
                                                 const float* __restrict__ gamma,
                                                 const float* __restrict__ beta,
                                                 unsigned short* __restrict__ h) {
  const int row  = blockIdx.x * 4 + (threadIdx.x >> 6);
  const int lane = threadIdx.x & 63;
  const float4* xr = (const float4*)(x + (size_t)row * DIM);
  float4 v[16];
  float s = 0.f, s2 = 0.f;
#pragma unroll
  for (int t = 0; t < 8; ++t) {
    const int idx = lane * 2 + t * 128;
    v[2 * t]     = xr[idx];
    v[2 * t + 1] = xr[idx + 1];
#pragma unroll
    for (int j = 0; j < 2; ++j) {
      const float4 q = v[2 * t + j];
      s  += q.x + q.y + q.z + q.w;
      s2 += q.x * q.x + q.y * q.y + q.z * q.z + q.w * q.w;
    }
  }
#pragma unroll
  for (int off = 32; off > 0; off >>= 1) {
    s  += __shfl_xor(s, off);
    s2 += __shfl_xor(s2, off);
  }
  const float mean = s * (1.f / DIM);
  const float var  = s2 * (1.f / DIM) - mean * mean;
  const float rstd = rsqrtf(var + EPSV);
  const float4* g4 = (const float4*)gamma;
  const float4* b4 = (const float4*)beta;
  US8* hr = (US8*)(h + (size_t)row * DIM);
#pragma unroll
  for (int t = 0; t < 8; ++t) {
    const int idx = lane * 2 + t * 128;
    US8 o;
#pragma unroll
    for (int j = 0; j < 2; ++j) {
      const float4 g = g4[idx + j], b = b4[idx + j], q = v[2 * t + j];
      o.u[4 * j + 0] = f2bf((q.x - mean) * rstd * g.x + b.x);
      o.u[4 * j + 1] = f2bf((q.y - mean) * rstd * g.y + b.y);
      o.u[4 * j + 2] = f2bf((q.z - mean) * rstd * g.z + b.z);
      o.u[4 * j + 3] = f2bf((q.w - mean) * rstd * g.w + b.w);
    }
    hr[lane + t * 64] = o;
  }
}

// ---------------- W fp32 -> bf16, 16B stores ----------------
__global__ __launch_bounds__(256) void wconv(const float* __restrict__ W,
                                             unsigned short* __restrict__ Wb) {
  const int i = blockIdx.x * 256 + threadIdx.x;  // US8 index
  const float4 w0 = ((const float4*)W)[2 * i];
  const float4 w1 = ((const float4*)W)[2 * i + 1];
  US8 o;
  o.u[0] = f2bf(w0.x); o.u[1] = f2bf(w0.y); o.u[2] = f2bf(w0.z); o.u[3] = f2bf(w0.w);
  o.u[4] = f2bf(w1.x); o.u[5] = f2bf(w1.y); o.u[6] = f2bf(w1.z); o.u[7] = f2bf(w1.w);
  ((US8*)Wb)[i] = o;
}

// ---------------- bf16 GEMM: 256x256 tile, 8-phase counted-vmcnt schedule ----------------
// 512 threads = 8 waves (2M x 4N); per-wave 128x64 output via 16x16x32 MFMA (acc[8][4]).
// LDS 128 KiB: double-buffered A,B K-tiles [256 rows][8 chunks of 16B], XOR-swizzled
// phys chunk = r*8 + (c ^ (r&7)); staged via pre-swizzled GLOBAL source (linear LDS dest).
// Per iteration (2 K-tiles E=buf0, O=buf1), 8 phases; stage 1 half-tile (2 gload_lds)
// per phase; vmcnt(4) only at phases 4/8; raw s_barrier (never __syncthreads) so the
// compiler never drains vmcnt at the barrier.
//
// Liveness (per iteration): buf0 B last read ph2, buf0 A ph3, buf1 B ph6, buf1 A ph7.
// Stage targets:  ph1: A.O h0 | ph2: A.O h1 | ph3: B.E' h0 | ph4: B.E' h1 |
//                 ph5: A.E' h0 | ph6: A.E' h1 | ph7: B.O' h0 | ph8: B.O' h1
// Gates: ph4 vmcnt(4) -> ph1..2 (A.O, read ph5/ph7) + all older landed.
//        ph8 vmcnt(4) -> ph5..6 (A.E', read next ph1/ph3) + all older landed.
template <int MH, int NH>
__device__ __forceinline__ void mma_q(floatx4 acc[8][4], const short8 a[2][4], const short8 b[2][2]) {
  __builtin_amdgcn_s_setprio(1);
#pragma unroll
  for (int ks = 0; ks < 2; ++ks)
#pragma unroll
    for (int mf = 0; mf < 4; ++mf)
#pragma unroll
      for (int nf = 0; nf < 2; ++nf)
        acc[MH * 4 + mf][NH * 2 + nf] = __builtin_amdgcn_mfma_f32_16x16x32_bf16(
            a[ks][mf], b[ks][nf], acc[MH * 4 + mf][NH * 2 + nf], 0, 0, 0);
  __builtin_amdgcn_s_setprio(0);
}

#define BAR()    __builtin_amdgcn_s_barrier()
#define LGKM0()  asm volatile("s_waitcnt lgkmcnt(0)" ::: "memory")
#define VMCNT4() asm volatile("s_waitcnt vmcnt(4)" ::: "memory")
#define VMCNT0() asm volatile("s_waitcnt vmcnt(0)" ::: "memory")

__global__ __launch_bounds__(512, 2) void gemm_bt(const unsigned short* __restrict__ A,
                                                  const unsigned short* __restrict__ B,
                                                  const float* __restrict__ bias,
                                                  float* __restrict__ out) {
  __shared__ short8 As8[4096];  // 2 bufs x 256 rows x 8 chunks = 64 KB
  __shared__ short8 Bs8[4096];  // 64 KB
  const int tid  = threadIdx.x;
  const int lane = tid & 63, wave = tid >> 6;
  const int warp_m = wave >> 2, warp_n = wave & 3;
  const int fr = lane & 15;   // fragment row within 16
  const int cg = lane >> 4;   // k chunk group 0..3

  // XCD-aware remap: xcd = pid&7 owns a 2-tile bn stripe (512 cols x 4096 K x 2B = 4MB
  // of B = one L2), walks bm; XCDs walk bm in lockstep so A-tiles hit the shared L3.
  const int pid = blockIdx.x;
  const int xcd = pid & 7;
  const int s   = pid >> 3;                    // [0,128)
  const int bm0 = (s >> 1) * 256;              // 64 bm tiles
  const int bn0 = (xcd * 2 + (s & 1)) * 256;   // 16 bn tiles

  auto stage = [&](const unsigned short* __restrict__ g, short8* lds, int rowbase, int k0, int h) {
#pragma unroll
    for (int i = 0; i < 2; ++i) {
      const int q = i * 512 + wave * 64 + lane;      // phys chunk within 16 KB half
      const int r = h * 128 + (q >> 3);              // tile row [0,256)
      const int c = (q & 7) ^ (r & 7);               // logical k-chunk (pre-swizzled src)
      const unsigned short* src = g + (size_t)(rowbase + r) * DIM + k0 + c * 8;
      __builtin_amdgcn_global_load_lds((const __attribute__((address_space(1))) void*)src,
                                       (__attribute__((address_space(3))) void*)(lds + h * 1024 + i * 512 + wave * 64),
                                       16, 0, 0);
    }
  };
  auto ld_a = [&](short8 a[2][4], int buf, int rbase) {
#pragma unroll
    for (int ks = 0; ks < 2; ++ks)
#pragma unroll
      for (int mf = 0; mf < 4; ++mf) {
        const int r = rbase + mf * 16 + fr;
        a[ks][mf] = As8[buf * 2048 + r * 8 + ((ks * 4 + cg) ^ (r & 7))];
      }
  };
  auto ld_b = [&](short8 b[2][2], int buf, int rbase) {
#pragma unroll
    for (int ks = 0; ks < 2; ++ks)
#pragma unroll
      for (int nf = 0; nf < 2; ++nf) {
        const int r = rbase + nf * 16 + fr;
        b[ks][nf] = Bs8[buf * 2048 + r * 8 + ((ks * 4 + cg) ^ (r & 7))];
      }
  };

  floatx4 acc[8][4];
#pragma unroll
  for (int i = 0; i < 8; ++i)
#pragma unroll
    for (int j = 0; j < 4; ++j)
#pragma unroll
      for (int r = 0; r < 4; ++r) acc[i][j][r] = 0.f;

  const int Ra0 = warp_m * 128;  // wave's A row base (LDS half = warp_m)
  const int Rb0 = warp_n * 64;   // wave's B row base

  // ---- prologue: tile0 (buf0) full + tile1 (buf1) B halves; 12 loads, keep 4 in flight
  stage(A, As8, bm0, 0, 0);
  stage(A, As8, bm0, 0, 1);
  stage(B, Bs8, bn0, 0, 0);
  stage(B, Bs8, bn0, 0, 1);
  stage(B, Bs8 + 2048, bn0, 64, 0);
  stage(B, Bs8 + 2048, bn0, 64, 1);
  VMCNT4();
  BAR();

  short8 a[2][4], b0[2][2], b1[2][2];

  for (int it = 0; it < NKT / 2; ++it) {
    const int kO  = it * 128 + 64;                                  // odd tile 2it+1 (buf1)
    const int kE2 = (2 * it + 2 < NKT ? 2 * it + 2 : NKT - 1) * 64; // next even tile (buf0)
    const int kO2 = (2 * it + 3 < NKT ? 2 * it + 3 : NKT - 1) * 64; // next odd tile (buf1)

    // ph1: ds A.E(mh0)+B.E(nh0); stage A.O h0; mma q0(E)
    ld_a(a, 0, Ra0);
    ld_b(b0, 0, Rb0);
    stage(A, As8 + 2048, bm0, kO, 0);
    BAR(); LGKM0();
    mma_q<0, 0>(acc, a, b0);
    BAR();

    // ph2: ds B.E(nh1); stage A.O h1; mma q1(E)
    ld_b(b1, 0, Rb0 + 32);
    stage(A, As8 + 2048, bm0, kO, 1);
    BAR(); LGKM0();
    mma_q<0, 1>(acc, a, b1);
    BAR();

    // ph3: ds A.E(mh1); stage B.E' h0; mma q2(E)
    ld_a(a, 0, Ra0 + 64);
    stage(B, Bs8, bn0, kE2, 0);
    BAR(); LGKM0();
    mma_q<1, 0>(acc, a, b0);
    BAR();

    // ph4: stage B.E' h1; vmcnt(4); mma q3(E)
    stage(B, Bs8, bn0, kE2, 1);
    VMCNT4();
    BAR(); LGKM0();
    mma_q<1, 1>(acc, a, b1);
    BAR();

    // ph5: ds A.O(mh0)+B.O(nh0); stage A.E' h0; mma q0(O)
    ld_a(a, 1, Ra0);
    ld_b(b0, 1, Rb0);
    stage(A, As8, bm0, kE2, 0);
    BAR(); LGKM0();
    mma_q<0, 0>(acc, a, b0);
    BAR();

    // ph6: ds B.O(nh1); stage A.E' h1; mma q1(O)
    ld_b(b1, 1, Rb0 + 32);
    stage(A, As8, bm0, kE2, 1);
    BAR(); LGKM0();
    mma_q<0, 1>(acc, a, b1);
    BAR();

    // ph7: ds A.O(mh1); stage B.O' h0; mma q2(O)
    ld_a(a, 1, Ra0 + 64);
    stage(B, Bs8 + 2048, bn0, kO2, 0);
    BAR(); LGKM0();
    mma_q<1, 0>(acc, a, b0);
    BAR();

    // ph8: stage B.O' h1; vmcnt(4); mma q3(O)
    stage(B, Bs8 + 2048, bn0, kO2, 1);
    VMCNT4();
    BAR(); LGKM0();
    mma_q<1, 1>(acc, a, b1);
    BAR();
  }

  // Drain the tail dummy stages before epilogue/endpgm: a late-landing global_load_lds
  // after LDS is reallocated to the next block would corrupt that block's tiles.
  VMCNT0();

  // Epilogue: 16x16x32 C/D layout col=lane&15, row=(lane>>4)*4+reg  [m89/m91]
#pragma unroll
  for (int nh = 0; nh < 2; ++nh)
#pragma unroll
    for (int nf = 0; nf < 2; ++nf) {
      const int col = bn0 + warp_n * 64 + nh * 32 + nf * 16 + fr;
      const float bv = bias[col];
#pragma unroll
      for (int mh = 0; mh < 2; ++mh)
#pragma unroll
        for (int mf = 0; mf < 4; ++mf) {
          const int rbase = bm0 + warp_m * 128 + mh * 64 + mf * 16 + cg * 4;
          const floatx4 v = acc[mh * 4 + mf][nh * 2 + nf];
#pragma unroll
          for (int r = 0; r < 4; ++r)
            out[(size_t)(rbase + r) * DIM + col] = fmaxf(v[r] + bv, 0.f);
        }
    }
}

// ---------------- fp32 fallback (only if ws too small) ----------------
__global__ __launch_bounds__(256) void fallback_kernel(const float* __restrict__ x,
                                                       const float* __restrict__ W,
                                                       const float* __restrict__ bias,
                                                       const float* __restrict__ gamma,
                                                       const float* __restrict__ beta,
                                                       float* __restrict__ out) {
  __shared__ float h[DIM];
  __shared__ float red[8];
  const int row = blockIdx.x, tid = threadIdx.x;
  const float4* xr = (const float4*)(x + (size_t)row * DIM);
  float s = 0.f, s2 = 0.f;
  float4 v[4];
#pragma unroll
  for (int i = 0; i < 4; ++i) {
    v[i] = xr[tid + i * 256];
    s  += v[i].x + v[i].y + v[i].z + v[i].w;
    s2 += v[i].x * v[i].x + v[i].y * v[i].y + v[i].z * v[i].z + v[i].w * v[i].w;
  }
#pragma unroll
  for (int off = 32; off > 0; off >>= 1) {
    s  += __shfl_down(s, off);
    s2 += __shfl_down(s2, off);
  }
  const int lane = tid & 63, wave = tid >> 6;
  if (lane == 0) { red[wave] = s; red[wave + 4] = s2; }
  __syncthreads();
  s  = red[0] + red[1] + red[2] + red[3];
  s2 = red[4] + red[5] + red[6] + red[7];
  const float mean = s * (1.f / DIM);
  const float var  = s2 * (1.f / DIM) - mean * mean;
  const float rstd = rsqrtf(var + EPSV);
#pragma unroll
  for (int i = 0; i < 4; ++i) {
    const int idx = tid + i * 256;
    const float4 g = ((const float4*)gamma)[idx];
    const float4 b = ((const float4*)beta)[idx];
    float4 o;
    o.x = (v[i].x - mean) * rstd * g.x + b.x;
    o.y = (v[i].y - mean) * rstd * g.y + b.y;
    o.z = (v[i].z - mean) * rstd * g.z + b.z;
    o.w = (v[i].w - mean) * rstd * g.w + b.w;
    ((float4*)h)[idx] = o;
  }
  __syncthreads();
  for (int n = tid; n < DIM; n += 256) {
    const float4* wr = (const float4*)(W + (size_t)n * DIM);
    float acc = 0.f;
    for (int k = 0; k < DIM / 4; ++k) {
      const float4 w = wr[k];
      const float4 hv = ((const float4*)h)[k];
      acc += hv.x * w.x + hv.y * w.y + hv.z * w.z + hv.w * w.w;
    }
    out[(size_t)row * DIM + n] = fmaxf(acc + bias[n], 0.f);
  }
}

extern "C" void kernel_launch(void* const* d_in, const int* in_sizes, int n_in,
                              void* d_out, int out_size, void* d_ws, size_t ws_size,
                              hipStream_t stream) {
  const float* x     = (const float*)d_in[0];
  const float* W     = (const float*)d_in[1];
  const float* b     = (const float*)d_in[2];
  const float* gamma = (const float*)d_in[3];
  const float* beta  = (const float*)d_in[4];
  float* out = (float*)d_out;

  const size_t h_elems = (size_t)MROWS * DIM;
  const size_t w_elems = (size_t)DIM * DIM;
  const size_t need = (h_elems + w_elems) * sizeof(unsigned short);  // 160 MB

  if (ws_size >= need) {
    unsigned short* h  = (unsigned short*)d_ws;
    unsigned short* Wb = h + h_elems;
    ln_kernel<<<MROWS / 4, 256, 0, stream>>>(x, gamma, beta, h);
    wconv<<<(int)(w_elems / 8 / 256), 256, 0, stream>>>(W, Wb);
    gemm_bt<<<(MROWS / 256) * (DIM / 256), 512, 0, stream>>>(h, Wb, b, out);
  } else {
    fallback_kernel<<<MROWS, 256, 0, stream>>>(x, W, b, gamma, beta, out);
  }
}